// Round 2
// baseline (1761.041 us; speedup 1.0000x reference)
//
#include <hip/hip_runtime.h>
#include <stdint.h>

typedef __bf16 bf16;
typedef __bf16 bf16x4 __attribute__((ext_vector_type(4)));
typedef __bf16 bf16x8 __attribute__((ext_vector_type(8)));
typedef float  f32x4  __attribute__((ext_vector_type(4)));

#define NLAYER 6
#define HDIM   1024
#define FFDIM  4096
#define NHEAD  8
#define HEADD  128
#define SEQ    1024
#define NTOK   4096   // B*S = 4*1024

__device__ __forceinline__ void g2l16(const void* g, void* l) {
  __builtin_amdgcn_global_load_lds(
      (const __attribute__((address_space(1))) void*)g,
      (__attribute__((address_space(3))) void*)l, 16, 0, 0);
}

// ---------------- weight convert: f32 -> bf16, 8 elems/thread ----------------
__global__ __launch_bounds__(256) void cvt_w(const float* __restrict__ in,
                                             bf16* __restrict__ out, int n8) {
  int i = blockIdx.x * 256 + threadIdx.x;
  if (i >= n8) return;
  const f32x4* p = (const f32x4*)in + (size_t)i * 2;
  f32x4 a = p[0], b = p[1];
  bf16x8 o;
  o[0] = (bf16)a[0]; o[1] = (bf16)a[1]; o[2] = (bf16)a[2]; o[3] = (bf16)a[3];
  o[4] = (bf16)b[0]; o[5] = (bf16)b[1]; o[6] = (bf16)b[2]; o[7] = (bf16)b[3];
  *((bf16x8*)out + i) = o;
}

// ---------------- LayerNorm: f32 in -> bf16 out, one block per row ----------
__global__ __launch_bounds__(256) void ln_k(const float* __restrict__ x,
                                            const float* __restrict__ sc,
                                            const float* __restrict__ bi,
                                            bf16* __restrict__ out) {
  int row = blockIdx.x, t = threadIdx.x;
  f32x4 v = *((const f32x4*)(x + (size_t)row * HDIM) + t);
  float s = v[0] + v[1] + v[2] + v[3];
  float q = v[0]*v[0] + v[1]*v[1] + v[2]*v[2] + v[3]*v[3];
#pragma unroll
  for (int m = 1; m < 64; m <<= 1) {
    s += __shfl_xor(s, m, 64);
    q += __shfl_xor(q, m, 64);
  }
  __shared__ float ss[4], qq[4];
  if ((t & 63) == 0) { ss[t >> 6] = s; qq[t >> 6] = q; }
  __syncthreads();
  s = ss[0] + ss[1] + ss[2] + ss[3];
  q = qq[0] + qq[1] + qq[2] + qq[3];
  float mu  = s * (1.f / HDIM);
  float var = q * (1.f / HDIM) - mu * mu;
  float rs  = rsqrtf(var + 1e-5f);
  f32x4 g = *((const f32x4*)sc + t);
  f32x4 b = *((const f32x4*)bi + t);
  bf16x4 o;
#pragma unroll
  for (int j = 0; j < 4; j++) o[j] = (bf16)((v[j] - mu) * rs * g[j] + b[j]);
  *((bf16x4*)(out + (size_t)row * HDIM) + t) = o;
}

// ---------------- GEMM  C[M,N] = A[M,K] * W[N,K]^T  (+bias,+relu,+resid) ----
// 128x128 tile, BK=64, 4 waves (2x2), 64x64 per wave, mfma 16x16x32 bf16.
// LDS rows are 128B; XOR-swizzle ((row&7)<<4) applied on BOTH the
// global_load_lds source column and the ds_read_b128 column (rule #21).
// SPLITV: cols [2048,3072) are the V part of the qkv output -> store
// transposed into vt[b][h][d][s] (bf16x4 along s) for attention PV.
template <bool RELU, bool RESID, bool OUTF32, bool SPLITV>
__global__ __launch_bounds__(256) void gemm_bt(const bf16* __restrict__ A,
                                               const bf16* __restrict__ W,
                                               const float* __restrict__ bias,
                                               const float* resid, void* outp,
                                               bf16* __restrict__ vt,
                                               int M, int N, int K) {
  constexpr int BK = 64;
  __shared__ bf16 As[128 * BK];
  __shared__ bf16 Bs[128 * BK];
  int tid = threadIdx.x;
  int lane = tid & 63, w = tid >> 6;
  int g = lane >> 4, r = lane & 15;
  int wr = w >> 1, wc = w & 1;
  int nbx = N >> 7;
  int bm = blockIdx.x / nbx, bn = blockIdx.x % nbx;
  const bf16* Ab = A + (size_t)bm * 128 * K;
  const bf16* Wb = W + (size_t)bn * 128 * K;
  f32x4 acc[4][4] = {};

  for (int k0 = 0; k0 < K; k0 += BK) {
#pragma unroll
    for (int i = 0; i < 4; ++i) {
      int cb = i * 256 + w * 64;        // wave-uniform chunk base
      int c  = cb + lane;               // 16B chunk id (1024 per tile)
      int row = c >> 3;                 // 8 chunks per 128B row
      int kk  = ((c & 7) ^ (row & 7)) << 3;  // pre-swizzled source col (elems)
      g2l16(Ab + (size_t)row * K + k0 + kk, (char*)As + cb * 16);
      g2l16(Wb + (size_t)row * K + k0 + kk, (char*)Bs + cb * 16);
    }
    __syncthreads();
#pragma unroll
    for (int ks = 0; ks < 2; ++ks) {
      bf16x8 af[4], bfr[4];
#pragma unroll
      for (int mi = 0; mi < 4; mi++) {
        int row = wr * 64 + mi * 16 + r;
        af[mi] = *(const bf16x8*)((const char*)As + row * 128 +
                                  ((ks * 64 + g * 16) ^ ((row & 7) << 4)));
      }
#pragma unroll
      for (int ni = 0; ni < 4; ni++) {
        int row = wc * 64 + ni * 16 + r;
        bfr[ni] = *(const bf16x8*)((const char*)Bs + row * 128 +
                                   ((ks * 64 + g * 16) ^ ((row & 7) << 4)));
      }
#pragma unroll
      for (int mi = 0; mi < 4; mi++)
#pragma unroll
        for (int ni = 0; ni < 4; ni++)
          acc[mi][ni] = __builtin_amdgcn_mfma_f32_16x16x32_bf16(
              af[mi], bfr[ni], acc[mi][ni], 0, 0, 0);
    }
    __syncthreads();
  }

  // epilogue: D col = lane&15, row = (lane>>4)*4 + j  (m89-verified)
#pragma unroll
  for (int ni = 0; ni < 4; ++ni) {
    int col = bn * 128 + wc * 64 + ni * 16 + r;
    float bv = bias[col];
    bool vpart = SPLITV && (bn * 128 + wc * 64 + ni * 16) >= 2048;  // wave-uniform
    if (vpart) {
      int hh = (col - 2048) >> 7, dd = col & 127;
#pragma unroll
      for (int mi = 0; mi < 4; ++mi) {
        int row0 = bm * 128 + wr * 64 + mi * 16 + g * 4;
        int bb = row0 >> 10, ss = row0 & 1023;
        bf16x4 o;
#pragma unroll
        for (int j = 0; j < 4; j++) o[j] = (bf16)(acc[mi][ni][j] + bv);
        *(bf16x4*)(vt + ((size_t)((bb * NHEAD + hh) * HEADD + dd)) * SEQ + ss) = o;
      }
    } else {
#pragma unroll
      for (int mi = 0; mi < 4; ++mi) {
        int row0 = bm * 128 + wr * 64 + mi * 16 + g * 4;
#pragma unroll
        for (int j = 0; j < 4; j++) {
          size_t idx = (size_t)(row0 + j) * N + col;
          float v = acc[mi][ni][j] + bv;
          if constexpr (RELU) v = fmaxf(v, 0.f);
          if constexpr (RESID) v += resid[idx];  // may alias outp: same-elem same-thread
          if constexpr (OUTF32) ((float*)outp)[idx] = v;
          else                  ((bf16*)outp)[idx] = (bf16)v;
        }
      }
    }
  }
}

// ---------------- flash attention ------------------------------------------
// grid (S/64, NH, B); 256 thr = 4 waves; each wave owns 16 q-rows.
// qkv[t, part*1024 + h*128 + d] holds Q (part 0) and K (part 1).
// V comes pre-transposed from the qkv GEMM: vt[b][h][d][s].
// K LDS: row-major 64x128 (256B rows), both-sides XOR swizzle.
// VT LDS: row-major 128(d)x64(c) (128B rows), both-sides XOR swizzle.
// P: per-wave row-major [16 q][64 c], swizzled; written scalar, read b128.
__global__ __launch_bounds__(256) void attn_k(const bf16* __restrict__ qkv,
                                              const bf16* __restrict__ vt,
                                              bf16* __restrict__ out) {
  __shared__ bf16 Ks[64 * 128];
  __shared__ bf16 VT[128 * 64];
  __shared__ bf16 Ps[4][1024];
  int qt = blockIdx.x, h = blockIdx.y, b = blockIdx.z;
  int tid = threadIdx.x, lane = tid & 63, w = tid >> 6;
  int g = lane >> 4, r = lane & 15;
  int q0 = qt * 64;
  size_t tok0 = (size_t)b * SEQ;
  char* psw = (char*)Ps + w * 2048;

  bf16x8 qf[4];
  {
    const bf16* qp = qkv + (tok0 + q0 + w * 16 + r) * 3072 + h * HEADD;
#pragma unroll
    for (int ks = 0; ks < 4; ks++) qf[ks] = *(const bf16x8*)(qp + ks * 32 + g * 8);
  }
  f32x4 oacc[8] = {};
  float mprev[4], lsum[4];
#pragma unroll
  for (int j = 0; j < 4; j++) { mprev[j] = -1e30f; lsum[j] = 0.f; }
  const float scl = 0.08838834764831845f;  // 1/sqrt(128)
  const bf16* vtb = vt + (size_t)(b * NHEAD + h) * HEADD * SEQ;

  for (int c0 = 0; c0 < SEQ; c0 += 64) {
    const bf16* kbase = qkv + (tok0 + c0) * 3072 + 1024 + h * HEADD;
#pragma unroll
    for (int i = 0; i < 4; i++) {
      int cb = i * 256 + w * 64;
      int c  = cb + lane;
      // K tile: 64 rows x 256B, 16 chunks/row, pre-swizzled source
      int krow = c >> 4;
      int kkk  = ((c & 15) ^ (krow & 7)) << 3;
      g2l16(kbase + (size_t)krow * 3072 + kkk, (char*)Ks + cb * 16);
      // VT tile: 128 rows (d) x 128B (64 c), 8 chunks/row, pre-swizzled source
      int vrow = c >> 3;
      int vcol = ((c & 7) ^ (vrow & 7)) << 3;
      g2l16(vtb + (size_t)vrow * SEQ + c0 + vcol, (char*)VT + cb * 16);
    }
    __syncthreads();

    // QK^T: S[q=4g+j][key=cb*16+r]
    f32x4 sacc[4] = {};
#pragma unroll
    for (int ks = 0; ks < 4; ks++) {
#pragma unroll
      for (int cb = 0; cb < 4; cb++) {
        int row = cb * 16 + r;
        bf16x8 kf = *(const bf16x8*)((const char*)Ks + row * 256 +
                                     ((ks * 64 + g * 16) ^ ((row & 7) << 4)));
        sacc[cb] = __builtin_amdgcn_mfma_f32_16x16x32_bf16(qf[ks], kf, sacc[cb], 0, 0, 0);
      }
    }
#pragma unroll
    for (int cb = 0; cb < 4; cb++) {
      sacc[cb][0] *= scl; sacc[cb][1] *= scl; sacc[cb][2] *= scl; sacc[cb][3] *= scl;
    }
    // online softmax (reduce across the 16 lanes r of each group g)
    float sf[4];
#pragma unroll
    for (int j = 0; j < 4; j++) {
      float m = fmaxf(fmaxf(sacc[0][j], sacc[1][j]), fmaxf(sacc[2][j], sacc[3][j]));
      m = fmaxf(m, __shfl_xor(m, 1, 64));
      m = fmaxf(m, __shfl_xor(m, 2, 64));
      m = fmaxf(m, __shfl_xor(m, 4, 64));
      m = fmaxf(m, __shfl_xor(m, 8, 64));
      float mn = fmaxf(mprev[j], m);
      float f  = __expf(mprev[j] - mn);
      mprev[j] = mn; sf[j] = f;
      float rs = 0.f;
#pragma unroll
      for (int cb = 0; cb < 4; cb++) {
        float p = __expf(sacc[cb][j] - mn);
        sacc[cb][j] = p; rs += p;
      }
      rs += __shfl_xor(rs, 1, 64);
      rs += __shfl_xor(rs, 2, 64);
      rs += __shfl_xor(rs, 4, 64);
      rs += __shfl_xor(rs, 8, 64);
      lsum[j] = lsum[j] * f + rs;
    }
#pragma unroll
    for (int nb = 0; nb < 8; nb++) {
      oacc[nb][0] *= sf[0]; oacc[nb][1] *= sf[1];
      oacc[nb][2] *= sf[2]; oacc[nb][3] *= sf[3];
    }
    // write P row-major [16 q][128B], swizzled ^((q&7)<<4); scalar u16 stores
#pragma unroll
    for (int cb = 0; cb < 4; cb++) {
      int cbyte = cb * 32 + r * 2;
#pragma unroll
      for (int j = 0; j < 4; j++) {
        int q = g * 4 + j;
        *(bf16*)(psw + q * 128 + (cbyte ^ ((q & 7) << 4))) = (bf16)sacc[cb][j];
      }
    }
    asm volatile("s_waitcnt lgkmcnt(0)" ::: "memory");
    __builtin_amdgcn_sched_barrier(0);
    // PV: O[q][d] += P[q][c] * V[c][d], via plain swizzled b128 reads
#pragma unroll
    for (int cs = 0; cs < 2; cs++) {
      bf16x8 pf = *(const bf16x8*)(psw + r * 128 + ((cs * 64 + g * 16) ^ ((r & 7) << 4)));
#pragma unroll
      for (int nb = 0; nb < 8; nb++) {
        int vrow = nb * 16 + r;
        bf16x8 vf = *(const bf16x8*)((const char*)VT + vrow * 128 +
                                     ((cs * 64 + g * 16) ^ ((vrow & 7) << 4)));
        oacc[nb] = __builtin_amdgcn_mfma_f32_16x16x32_bf16(pf, vf, oacc[nb], 0, 0, 0);
      }
    }
    __syncthreads();
  }

  float rl[4];
#pragma unroll
  for (int j = 0; j < 4; j++) rl[j] = 1.f / lsum[j];
#pragma unroll
  for (int nb = 0; nb < 8; nb++)
#pragma unroll
    for (int j = 0; j < 4; j++)
      out[(tok0 + q0 + w * 16 + g * 4 + j) * HDIM + h * HEADD + nb * 16 + r] =
          (bf16)(oacc[nb][j] * rl[j]);
}

// ---------------------------------------------------------------------------
extern "C" void kernel_launch(void* const* d_in, const int* in_sizes, int n_in,
                              void* d_out, int out_size, void* d_ws, size_t ws_size,
                              hipStream_t stream) {
  const float* x_in   = (const float*)d_in[0];
  const float* qkv_w  = (const float*)d_in[1];
  const float* qkv_b  = (const float*)d_in[2];
  const float* proj_w = (const float*)d_in[3];
  const float* proj_b = (const float*)d_in[4];
  const float* fc1_w  = (const float*)d_in[5];
  const float* fc1_b  = (const float*)d_in[6];
  const float* fc2_w  = (const float*)d_in[7];
  const float* fc2_b  = (const float*)d_in[8];
  const float* ln1_s  = (const float*)d_in[9];
  const float* ln1_b  = (const float*)d_in[10];
  const float* ln2_s  = (const float*)d_in[11];
  const float* ln2_b  = (const float*)d_in[12];

  char* ws = (char*)d_ws;
  size_t o = 0;
  bf16* Wq = (bf16*)(ws + o); o += (size_t)NLAYER * 3 * HDIM * HDIM * 2;   // 37.7MB
  bf16* Wp = (bf16*)(ws + o); o += (size_t)NLAYER * HDIM * HDIM * 2;       // 12.6MB
  bf16* W1 = (bf16*)(ws + o); o += (size_t)NLAYER * FFDIM * HDIM * 2;      // 50.3MB
  bf16* W2 = (bf16*)(ws + o); o += (size_t)NLAYER * HDIM * FFDIM * 2;      // 50.3MB
  bf16* hx   = (bf16*)(ws + o); o += (size_t)NTOK * HDIM * 2;              // 8.4MB
  bf16* qkvb = (bf16*)(ws + o); o += (size_t)NTOK * 3 * HDIM * 2;          // 25.2MB
  bf16* Vt   = (bf16*)(ws + o); o += (size_t)NTOK * HDIM * 2;              // 8.4MB
  bf16* aout = (bf16*)(ws + o); o += (size_t)NTOK * HDIM * 2;              // 8.4MB
  bf16* ffb  = (bf16*)(ws + o); o += (size_t)NTOK * FFDIM * 2;             // 33.6MB
  float* xbuf = (float*)d_out;  // residual stream lives in d_out (f32)

  // weights -> bf16 (exact: values are fp8-roundtripped)
  {
    int n8;
    n8 = NLAYER * 3 * HDIM * HDIM / 8;
    cvt_w<<<(n8 + 255) / 256, 256, 0, stream>>>(qkv_w, Wq, n8);
    n8 = NLAYER * HDIM * HDIM / 8;
    cvt_w<<<(n8 + 255) / 256, 256, 0, stream>>>(proj_w, Wp, n8);
    n8 = NLAYER * FFDIM * HDIM / 8;
    cvt_w<<<(n8 + 255) / 256, 256, 0, stream>>>(fc1_w, W1, n8);
    n8 = NLAYER * HDIM * FFDIM / 8;
    cvt_w<<<(n8 + 255) / 256, 256, 0, stream>>>(fc2_w, W2, n8);
  }

  for (int i = 0; i < NLAYER; i++) {
    const float* xc = (i == 0) ? x_in : xbuf;
    // attention block
    ln_k<<<NTOK, 256, 0, stream>>>(xc, ln1_s + i * HDIM, ln1_b + i * HDIM, hx);
    gemm_bt<false, false, false, true><<<(NTOK / 128) * (3 * HDIM / 128), 256, 0, stream>>>(
        hx, Wq + (size_t)i * 3 * HDIM * HDIM, qkv_b + i * 3 * HDIM, nullptr,
        qkvb, Vt, NTOK, 3 * HDIM, HDIM);
    attn_k<<<dim3(SEQ / 64, NHEAD, 4), 256, 0, stream>>>(qkvb, Vt, aout);
    gemm_bt<false, true, true, false><<<(NTOK / 128) * (HDIM / 128), 256, 0, stream>>>(
        aout, Wp + (size_t)i * HDIM * HDIM, proj_b + i * HDIM, xc,
        xbuf, nullptr, NTOK, HDIM, HDIM);
    // FFN block
    ln_k<<<NTOK, 256, 0, stream>>>(xbuf, ln2_s + i * HDIM, ln2_b + i * HDIM, hx);
    gemm_bt<true, false, false, false><<<(NTOK / 128) * (FFDIM / 128), 256, 0, stream>>>(
        hx, W1 + (size_t)i * FFDIM * HDIM, fc1_b + i * FFDIM, nullptr,
        ffb, nullptr, NTOK, FFDIM, HDIM);
    gemm_bt<false, true, true, false><<<(NTOK / 128) * (HDIM / 128), 256, 0, stream>>>(
        ffb, W2 + (size_t)i * HDIM * FFDIM, fc2_b + i * HDIM, xbuf,
        xbuf, nullptr, NTOK, HDIM, FFDIM);
  }
  (void)in_sizes; (void)n_in; (void)out_size; (void)ws_size;
}

// Round 3
// 1567.014 us; speedup vs baseline: 1.1238x; 1.1238x over previous
//
#include <hip/hip_runtime.h>
#include <stdint.h>

typedef __bf16 bf16;
typedef __bf16 bf16x4 __attribute__((ext_vector_type(4)));
typedef __bf16 bf16x8 __attribute__((ext_vector_type(8)));
typedef float  f32x4  __attribute__((ext_vector_type(4)));

#define NLAYER 6
#define HDIM   1024
#define FFDIM  4096
#define NHEAD  8
#define HEADD  128
#define SEQ    1024
#define NTOK   4096   // B*S = 4*1024

__device__ __forceinline__ void g2l16(const void* g, void* l) {
  __builtin_amdgcn_global_load_lds(
      (const __attribute__((address_space(1))) void*)g,
      (__attribute__((address_space(3))) void*)l, 16, 0, 0);
}

// ---------------- weight convert: f32 -> bf16, 8 elems/thread ----------------
__global__ __launch_bounds__(256) void cvt_w(const float* __restrict__ in,
                                             bf16* __restrict__ out, int n8) {
  int i = blockIdx.x * 256 + threadIdx.x;
  if (i >= n8) return;
  const f32x4* p = (const f32x4*)in + (size_t)i * 2;
  f32x4 a = p[0], b = p[1];
  bf16x8 o;
  o[0] = (bf16)a[0]; o[1] = (bf16)a[1]; o[2] = (bf16)a[2]; o[3] = (bf16)a[3];
  o[4] = (bf16)b[0]; o[5] = (bf16)b[1]; o[6] = (bf16)b[2]; o[7] = (bf16)b[3];
  *((bf16x8*)out + i) = o;
}

// ---------------- LayerNorm: f32 in -> bf16 out, one block per row ----------
__global__ __launch_bounds__(256) void ln_k(const float* __restrict__ x,
                                            const float* __restrict__ sc,
                                            const float* __restrict__ bi,
                                            bf16* __restrict__ out) {
  int row = blockIdx.x, t = threadIdx.x;
  f32x4 v = *((const f32x4*)(x + (size_t)row * HDIM) + t);
  float s = v[0] + v[1] + v[2] + v[3];
  float q = v[0]*v[0] + v[1]*v[1] + v[2]*v[2] + v[3]*v[3];
#pragma unroll
  for (int m = 1; m < 64; m <<= 1) {
    s += __shfl_xor(s, m, 64);
    q += __shfl_xor(q, m, 64);
  }
  __shared__ float ss[4], qq[4];
  if ((t & 63) == 0) { ss[t >> 6] = s; qq[t >> 6] = q; }
  __syncthreads();
  s = ss[0] + ss[1] + ss[2] + ss[3];
  q = qq[0] + qq[1] + qq[2] + qq[3];
  float mu  = s * (1.f / HDIM);
  float var = q * (1.f / HDIM) - mu * mu;
  float rs  = rsqrtf(var + 1e-5f);
  f32x4 g = *((const f32x4*)sc + t);
  f32x4 b = *((const f32x4*)bi + t);
  bf16x4 o;
#pragma unroll
  for (int j = 0; j < 4; j++) o[j] = (bf16)((v[j] - mu) * rs * g[j] + b[j]);
  *((bf16x4*)(out + (size_t)row * HDIM) + t) = o;
}

// ---------------- GEMM  C[M,N] = A[M,K] * W[N,K]^T  (+bias,+relu,+resid) ----
// 512 thr = 8 waves (2M x 4N), 128x128 tile, BK=64, 64x32 per wave.
// Double-buffered LDS, 2-phase schedule (T3-min): STAGE(next) issued BEFORE
// compute(cur); one vmcnt(0)+barrier per K-step (inside __syncthreads).
// Both-sides XOR swizzle ^((row&7)<<4) on 128B LDS rows (rule #21).
// T5: setprio(1) around MFMA cluster.  T1: bijective XCD swizzle (nwg%8==0).
// SPLITV: cols [2048,3072) of qkv output stored transposed to vt[b][h][d][s].
template <bool RELU, bool RESID, bool OUTF32, bool SPLITV>
__global__ __launch_bounds__(512) void gemm8(const bf16* __restrict__ A,
                                             const bf16* __restrict__ W,
                                             const float* __restrict__ bias,
                                             const float* resid, void* outp,
                                             bf16* __restrict__ vt,
                                             int M, int N, int K) {
  __shared__ bf16 As[2][128 * 64];
  __shared__ bf16 Bs[2][128 * 64];
  int tid = threadIdx.x;
  int lane = tid & 63, w = tid >> 6;
  int g = lane >> 4, r = lane & 15;
  int wr = w >> 2, wc = w & 3;                    // 2M x 4N wave grid
  int nbx = N >> 7;
  // T1: XCD-aware bijective swizzle (all grids here are %8 == 0)
  int cpx = gridDim.x >> 3;
  int swz = (blockIdx.x & 7) * cpx + (blockIdx.x >> 3);
  int bm = swz / nbx, bn = swz % nbx;
  const bf16* Ab = A + (size_t)bm * 128 * K;
  const bf16* Wb = W + (size_t)bn * 128 * K;
  f32x4 acc[4][2] = {};

  auto STAGE = [&](int buf, int k0) {
#pragma unroll
    for (int i = 0; i < 2; ++i) {
      int c = i * 512 + tid;                 // 16B chunk id, 1024 per tile
      int row = c >> 3;                      // 8 chunks per 128B row
      int kk = ((c & 7) ^ (row & 7)) << 3;   // pre-swizzled source col (elems)
      g2l16(Ab + (size_t)row * K + k0 + kk, (char*)As[buf] + c * 16);
      g2l16(Wb + (size_t)row * K + k0 + kk, (char*)Bs[buf] + c * 16);
    }
  };
  auto COMPUTE = [&](int buf) {
#pragma unroll
    for (int ks = 0; ks < 2; ++ks) {
      bf16x8 af[4], bfr[2];
#pragma unroll
      for (int mi = 0; mi < 4; mi++) {
        int row = wr * 64 + mi * 16 + r;
        af[mi] = *(const bf16x8*)((const char*)As[buf] + row * 128 +
                                  ((ks * 64 + g * 16) ^ ((row & 7) << 4)));
      }
#pragma unroll
      for (int ni = 0; ni < 2; ni++) {
        int row = wc * 32 + ni * 16 + r;
        bfr[ni] = *(const bf16x8*)((const char*)Bs[buf] + row * 128 +
                                   ((ks * 64 + g * 16) ^ ((row & 7) << 4)));
      }
      __builtin_amdgcn_s_setprio(1);
#pragma unroll
      for (int mi = 0; mi < 4; mi++)
#pragma unroll
        for (int ni = 0; ni < 2; ni++)
          acc[mi][ni] = __builtin_amdgcn_mfma_f32_16x16x32_bf16(
              af[mi], bfr[ni], acc[mi][ni], 0, 0, 0);
      __builtin_amdgcn_s_setprio(0);
    }
  };

  int nt = K >> 6;
  STAGE(0, 0);
  __syncthreads();                 // drains vmcnt(0): tile 0 resident
  int cur = 0;
  for (int t = 0; t < nt - 1; ++t) {
    STAGE(cur ^ 1, (t + 1) << 6);  // loads fly under compute(cur)
    COMPUTE(cur);
    __syncthreads();               // vmcnt(0)+lgkmcnt(0)+barrier: next ready
    cur ^= 1;
  }
  COMPUTE(cur);

  // epilogue: D col = lane&15, row = (lane>>4)*4 + j  (m89-verified)
#pragma unroll
  for (int ni = 0; ni < 2; ++ni) {
    int col = bn * 128 + wc * 32 + ni * 16 + r;
    float bv = bias[col];
    bool vpart = SPLITV && (bn * 128 + wc * 32 + ni * 16) >= 2048;  // wave-uniform
    if (vpart) {
      int hh = (col - 2048) >> 7, dd = col & 127;
#pragma unroll
      for (int mi = 0; mi < 4; ++mi) {
        int row0 = bm * 128 + wr * 64 + mi * 16 + g * 4;
        int bb = row0 >> 10, ss = row0 & 1023;
        bf16x4 o;
#pragma unroll
        for (int j = 0; j < 4; j++) o[j] = (bf16)(acc[mi][ni][j] + bv);
        *(bf16x4*)(vt + ((size_t)((bb * NHEAD + hh) * HEADD + dd)) * SEQ + ss) = o;
      }
    } else {
#pragma unroll
      for (int mi = 0; mi < 4; ++mi) {
        int row0 = bm * 128 + wr * 64 + mi * 16 + g * 4;
#pragma unroll
        for (int j = 0; j < 4; j++) {
          size_t idx = (size_t)(row0 + j) * N + col;
          float v = acc[mi][ni][j] + bv;
          if constexpr (RELU) v = fmaxf(v, 0.f);
          if constexpr (RESID) v += resid[idx];  // may alias outp: same-elem same-thread
          if constexpr (OUTF32) ((float*)outp)[idx] = v;
          else                  ((bf16*)outp)[idx] = (bf16)v;
        }
      }
    }
  }
}

// ---------------- flash attention ------------------------------------------
// grid (S/64, NH, B); 256 thr = 4 waves; each wave owns 16 q-rows.
// qkv[t, part*1024 + h*128 + d] holds Q (part 0) and K (part 1).
// V comes pre-transposed from the qkv GEMM: vt[b][h][d][s].
// K LDS: row-major 64x128 (256B rows), both-sides XOR swizzle.
// VT LDS: row-major 128(d)x64(c) (128B rows), both-sides XOR swizzle.
// P: per-wave row-major [16 q][64 c], swizzled; written scalar, read b128.
__global__ __launch_bounds__(256) void attn_k(const bf16* __restrict__ qkv,
                                              const bf16* __restrict__ vt,
                                              bf16* __restrict__ out) {
  __shared__ bf16 Ks[64 * 128];
  __shared__ bf16 VT[128 * 64];
  __shared__ bf16 Ps[4][1024];
  int qt = blockIdx.x, h = blockIdx.y, b = blockIdx.z;
  int tid = threadIdx.x, lane = tid & 63, w = tid >> 6;
  int g = lane >> 4, r = lane & 15;
  int q0 = qt * 64;
  size_t tok0 = (size_t)b * SEQ;
  char* psw = (char*)Ps + w * 2048;

  bf16x8 qf[4];
  {
    const bf16* qp = qkv + (tok0 + q0 + w * 16 + r) * 3072 + h * HEADD;
#pragma unroll
    for (int ks = 0; ks < 4; ks++) qf[ks] = *(const bf16x8*)(qp + ks * 32 + g * 8);
  }
  f32x4 oacc[8] = {};
  float mprev[4], lsum[4];
#pragma unroll
  for (int j = 0; j < 4; j++) { mprev[j] = -1e30f; lsum[j] = 0.f; }
  const float scl = 0.08838834764831845f;  // 1/sqrt(128)
  const bf16* vtb = vt + (size_t)(b * NHEAD + h) * HEADD * SEQ;

  for (int c0 = 0; c0 < SEQ; c0 += 64) {
    const bf16* kbase = qkv + (tok0 + c0) * 3072 + 1024 + h * HEADD;
#pragma unroll
    for (int i = 0; i < 4; i++) {
      int cb = i * 256 + w * 64;
      int c  = cb + lane;
      // K tile: 64 rows x 256B, 16 chunks/row, pre-swizzled source
      int krow = c >> 4;
      int kkk  = ((c & 15) ^ (krow & 7)) << 3;
      g2l16(kbase + (size_t)krow * 3072 + kkk, (char*)Ks + cb * 16);
      // VT tile: 128 rows (d) x 128B (64 c), 8 chunks/row, pre-swizzled source
      int vrow = c >> 3;
      int vcol = ((c & 7) ^ (vrow & 7)) << 3;
      g2l16(vtb + (size_t)vrow * SEQ + c0 + vcol, (char*)VT + cb * 16);
    }
    __syncthreads();

    // QK^T: S[q=4g+j][key=cb*16+r]
    f32x4 sacc[4] = {};
#pragma unroll
    for (int ks = 0; ks < 4; ks++) {
#pragma unroll
      for (int cb = 0; cb < 4; cb++) {
        int row = cb * 16 + r;
        bf16x8 kf = *(const bf16x8*)((const char*)Ks + row * 256 +
                                     ((ks * 64 + g * 16) ^ ((row & 7) << 4)));
        sacc[cb] = __builtin_amdgcn_mfma_f32_16x16x32_bf16(qf[ks], kf, sacc[cb], 0, 0, 0);
      }
    }
#pragma unroll
    for (int cb = 0; cb < 4; cb++) {
      sacc[cb][0] *= scl; sacc[cb][1] *= scl; sacc[cb][2] *= scl; sacc[cb][3] *= scl;
    }
    // online softmax (reduce across the 16 lanes r of each group g)
    float sf[4];
#pragma unroll
    for (int j = 0; j < 4; j++) {
      float m = fmaxf(fmaxf(sacc[0][j], sacc[1][j]), fmaxf(sacc[2][j], sacc[3][j]));
      m = fmaxf(m, __shfl_xor(m, 1, 64));
      m = fmaxf(m, __shfl_xor(m, 2, 64));
      m = fmaxf(m, __shfl_xor(m, 4, 64));
      m = fmaxf(m, __shfl_xor(m, 8, 64));
      float mn = fmaxf(mprev[j], m);
      float f  = __expf(mprev[j] - mn);
      mprev[j] = mn; sf[j] = f;
      float rs = 0.f;
#pragma unroll
      for (int cb = 0; cb < 4; cb++) {
        float p = __expf(sacc[cb][j] - mn);
        sacc[cb][j] = p; rs += p;
      }
      rs += __shfl_xor(rs, 1, 64);
      rs += __shfl_xor(rs, 2, 64);
      rs += __shfl_xor(rs, 4, 64);
      rs += __shfl_xor(rs, 8, 64);
      lsum[j] = lsum[j] * f + rs;
    }
#pragma unroll
    for (int nb = 0; nb < 8; nb++) {
      oacc[nb][0] *= sf[0]; oacc[nb][1] *= sf[1];
      oacc[nb][2] *= sf[2]; oacc[nb][3] *= sf[3];
    }
    // write P row-major [16 q][128B], swizzled ^((q&7)<<4); scalar u16 stores
#pragma unroll
    for (int cb = 0; cb < 4; cb++) {
      int cbyte = cb * 32 + r * 2;
#pragma unroll
      for (int j = 0; j < 4; j++) {
        int q = g * 4 + j;
        *(bf16*)(psw + q * 128 + (cbyte ^ ((q & 7) << 4))) = (bf16)sacc[cb][j];
      }
    }
    asm volatile("s_waitcnt lgkmcnt(0)" ::: "memory");
    __builtin_amdgcn_sched_barrier(0);
    // PV: O[q][d] += P[q][c] * V[c][d], via plain swizzled b128 reads
#pragma unroll
    for (int cs = 0; cs < 2; cs++) {
      bf16x8 pf = *(const bf16x8*)(psw + r * 128 + ((cs * 64 + g * 16) ^ ((r & 7) << 4)));
#pragma unroll
      for (int nb = 0; nb < 8; nb++) {
        int vrow = nb * 16 + r;
        bf16x8 vf = *(const bf16x8*)((const char*)VT + vrow * 128 +
                                     ((cs * 64 + g * 16) ^ ((vrow & 7) << 4)));
        oacc[nb] = __builtin_amdgcn_mfma_f32_16x16x32_bf16(pf, vf, oacc[nb], 0, 0, 0);
      }
    }
    __syncthreads();
  }

  float rl[4];
#pragma unroll
  for (int j = 0; j < 4; j++) rl[j] = 1.f / lsum[j];
#pragma unroll
  for (int nb = 0; nb < 8; nb++)
#pragma unroll
    for (int j = 0; j < 4; j++)
      out[(tok0 + q0 + w * 16 + g * 4 + j) * HDIM + h * HEADD + nb * 16 + r] =
          (bf16)(oacc[nb][j] * rl[j]);
}

// ---------------------------------------------------------------------------
extern "C" void kernel_launch(void* const* d_in, const int* in_sizes, int n_in,
                              void* d_out, int out_size, void* d_ws, size_t ws_size,
                              hipStream_t stream) {
  const float* x_in   = (const float*)d_in[0];
  const float* qkv_w  = (const float*)d_in[1];
  const float* qkv_b  = (const float*)d_in[2];
  const float* proj_w = (const float*)d_in[3];
  const float* proj_b = (const float*)d_in[4];
  const float* fc1_w  = (const float*)d_in[5];
  const float* fc1_b  = (const float*)d_in[6];
  const float* fc2_w  = (const float*)d_in[7];
  const float* fc2_b  = (const float*)d_in[8];
  const float* ln1_s  = (const float*)d_in[9];
  const float* ln1_b  = (const float*)d_in[10];
  const float* ln2_s  = (const float*)d_in[11];
  const float* ln2_b  = (const float*)d_in[12];

  char* ws = (char*)d_ws;
  size_t o = 0;
  bf16* Wq = (bf16*)(ws + o); o += (size_t)NLAYER * 3 * HDIM * HDIM * 2;   // 37.7MB
  bf16* Wp = (bf16*)(ws + o); o += (size_t)NLAYER * HDIM * HDIM * 2;       // 12.6MB
  bf16* W1 = (bf16*)(ws + o); o += (size_t)NLAYER * FFDIM * HDIM * 2;      // 50.3MB
  bf16* W2 = (bf16*)(ws + o); o += (size_t)NLAYER * HDIM * FFDIM * 2;      // 50.3MB
  bf16* hx   = (bf16*)(ws + o); o += (size_t)NTOK * HDIM * 2;              // 8.4MB
  bf16* qkvb = (bf16*)(ws + o); o += (size_t)NTOK * 3 * HDIM * 2;          // 25.2MB
  bf16* Vt   = (bf16*)(ws + o); o += (size_t)NTOK * HDIM * 2;              // 8.4MB
  bf16* aout = (bf16*)(ws + o); o += (size_t)NTOK * HDIM * 2;              // 8.4MB
  bf16* ffb  = (bf16*)(ws + o); o += (size_t)NTOK * FFDIM * 2;             // 33.6MB
  float* xbuf = (float*)d_out;  // residual stream lives in d_out (f32)

  // weights -> bf16 (exact: values are fp8-roundtripped)
  {
    int n8;
    n8 = NLAYER * 3 * HDIM * HDIM / 8;
    cvt_w<<<(n8 + 255) / 256, 256, 0, stream>>>(qkv_w, Wq, n8);
    n8 = NLAYER * HDIM * HDIM / 8;
    cvt_w<<<(n8 + 255) / 256, 256, 0, stream>>>(proj_w, Wp, n8);
    n8 = NLAYER * FFDIM * HDIM / 8;
    cvt_w<<<(n8 + 255) / 256, 256, 0, stream>>>(fc1_w, W1, n8);
    n8 = NLAYER * HDIM * FFDIM / 8;
    cvt_w<<<(n8 + 255) / 256, 256, 0, stream>>>(fc2_w, W2, n8);
  }

  for (int i = 0; i < NLAYER; i++) {
    const float* xc = (i == 0) ? x_in : xbuf;
    // attention block
    ln_k<<<NTOK, 256, 0, stream>>>(xc, ln1_s + i * HDIM, ln1_b + i * HDIM, hx);
    gemm8<false, false, false, true><<<(NTOK / 128) * (3 * HDIM / 128), 512, 0, stream>>>(
        hx, Wq + (size_t)i * 3 * HDIM * HDIM, qkv_b + i * 3 * HDIM, nullptr,
        qkvb, Vt, NTOK, 3 * HDIM, HDIM);
    attn_k<<<dim3(SEQ / 64, NHEAD, 4), 256, 0, stream>>>(qkvb, Vt, aout);
    gemm8<false, true, true, false><<<(NTOK / 128) * (HDIM / 128), 512, 0, stream>>>(
        aout, Wp + (size_t)i * HDIM * HDIM, proj_b + i * HDIM, xc,
        xbuf, nullptr, NTOK, HDIM, HDIM);
    // FFN block
    ln_k<<<NTOK, 256, 0, stream>>>(xbuf, ln2_s + i * HDIM, ln2_b + i * HDIM, hx);
    gemm8<true, false, false, false><<<(NTOK / 128) * (FFDIM / 128), 512, 0, stream>>>(
        hx, W1 + (size_t)i * FFDIM * HDIM, fc1_b + i * FFDIM, nullptr,
        ffb, nullptr, NTOK, FFDIM, HDIM);
    gemm8<false, true, true, false><<<(NTOK / 128) * (HDIM / 128), 512, 0, stream>>>(
        ffb, W2 + (size_t)i * HDIM * FFDIM, fc2_b + i * HDIM, xbuf,
        xbuf, nullptr, NTOK, HDIM, FFDIM);
  }
  (void)in_sizes; (void)n_in; (void)out_size; (void)ws_size;
}